// Round 13
// baseline (43.893 us; speedup 1.0000x reference)
//
#include <hip/hip_runtime.h>
#include <math.h>

// Problem constants (B=1, C=64, H=W=256, N=4096, T=0.1)
#define HW2     65536
#define NLOC    4096
#define NROW    8192
#define CDIM    64
#define TINV    10.0f
#define EXP10   22026.465794806718f   // exp(1/T)
#define NP      64                    // 128-row panels
#define NPAIR   2080                  // NP*(NP+1)/2
#define SBLK    1024                  // simsum blocks (4/CU), grid-strided

#if __has_builtin(__builtin_amdgcn_exp2f)
#define ASCALE  14.426950408889634f   // 10 * log2(e)
#define EXPFN(x) __builtin_amdgcn_exp2f(x)
#else
#define ASCALE  10.0f
#define EXPFN(x) __expf(x)
#endif

typedef __attribute__((ext_vector_type(8))) short bf16x8;
typedef __attribute__((ext_vector_type(4))) float f32x4;
typedef unsigned short u16;

__device__ __forceinline__ unsigned short f2bf(float f) {
  unsigned u = __builtin_bit_cast(unsigned, f);
  u += 0x7FFFu + ((u >> 16) & 1u);   // RNE
  return (unsigned short)(u >> 16);
}
__device__ __forceinline__ float bf2f(unsigned u16v) {
  unsigned u = u16v << 16;
  return __builtin_bit_cast(float, u);
}
// Scale a bf16x8 fragment by ASCALE with RNE re-round (bit-identical to a
// materialized Ga; validated R9-R12, absmax 0).
__device__ __forceinline__ bf16x8 scale8(bf16x8 r) {
  bf16x8 o;
#pragma unroll
  for (int j = 0; j < 8; ++j)
    o[j] = (short)f2bf(bf2f((unsigned short)r[j]) * ASCALE);
  return o;
}

// Triangular decode: b -> (p,q), p<=q (same arithmetic as R6-R12, absmax 0).
__device__ __forceinline__ void tri_decode(int b, int* pOut, int* qOut) {
  int p = (int)((129.0f - sqrtf(16641.0f - 8.0f * (float)b)) * 0.5f);
  if (p < 0) p = 0;
  if (p > NP - 1) p = NP - 1;
#pragma unroll
  for (int it = 0; it < 3; ++it) {
    if (p > 0 && (p * NP - p * (p - 1) / 2) > b) --p;
    else if (((p + 1) * NP - (p + 1) * p / 2) <= b) ++p;
  }
  *pOut = p;
  *qOut = p + (b - (p * NP - p * (p - 1) / 2));
}

// ---------------------------------------------------------------------------
// Kernel GC (channel-major gather) — R8/R12-proven shape, verbatim.
// ---------------------------------------------------------------------------
__global__ __launch_bounds__(256) void gatherc_kernel(
    const float* __restrict__ emb0, const float* __restrict__ emb1,
    const float* __restrict__ loc0, const float* __restrict__ loc1,
    u16* __restrict__ Gb, unsigned* __restrict__ counter) {
  __shared__ int ind[64];
  __shared__ u16 Gs[64][18];          // pad 18: row stride 9 banks, coprime 32

  const int tid   = threadIdx.x;
  const int chunk = blockIdx.x;       // 0..127 -> rows chunk*64..+64
  const int cg    = blockIdx.y;       // 0..3   -> channels cg*16..+16
  const int eb    = chunk >> 6;
  const float* emb = eb ? emb1 : emb0;
  const float* loc = eb ? loc1 : loc0;

  if (chunk == 0 && cg == 0 && tid == 0) *counter = 0u;

  if (tid < 64) {
    const int u = (chunk & 63) * 64 + tid;
    float2 lv = *reinterpret_cast<const float2*>(&loc[u * 2]);
    ind[tid] = (int)floorf(lv.x) * 256 + (int)floorf(lv.y);
  }
  __syncthreads();

  const int row = tid & 63;
  const int cq  = tid >> 6;           // 0..3
  const int pos = ind[row];
#pragma unroll
  for (int k = 0; k < 4; ++k) {
    const int cl = cq + 4 * k;        // 0..15, each (row,cl) exactly once
    float v = emb[(size_t)(cg * 16 + cl) * HW2 + pos];
    Gs[row][cl] = f2bf(v);
  }
  __syncthreads();

  if (tid < 128) {
    const int r2 = tid >> 1, h = tid & 1;
    bf16x8 v = *reinterpret_cast<const bf16x8*>(&Gs[r2][h * 8]);
    *reinterpret_cast<bf16x8*>(
        &Gb[(size_t)(chunk * 64 + r2) * CDIM + cg * 16 + h * 8]) = v;
  }
}

// ---------------------------------------------------------------------------
// Staging one 64-row x 128B subtile into `base + half*4096` (u16 units),
// XOR seg-swizzle (measured 0 conflicts).  Linear LDS dest + inverse-
// swizzled global source (rule #21).
// ---------------------------------------------------------------------------
__device__ __forceinline__ void stage_tile(u16* base, const u16* __restrict__ Gb,
                                           int jb, int half, int tid, int wave,
                                           int srow, int ssl) {
#pragma unroll
  for (int r = 0; r < 2; ++r) {
    const u16* src = Gb + (size_t)(jb + r * 32 + srow) * CDIM + ssl * 8;
#if __has_builtin(__builtin_amdgcn_global_load_lds)
    u16* dst = base + half * 4096 + r * 2048 + wave * 512;
    __builtin_amdgcn_global_load_lds(
        (const __attribute__((address_space(1))) unsigned int*)src,
        (__attribute__((address_space(3))) unsigned int*)dst, 16, 0, 0);
#else
    bf16x8 tmp = *reinterpret_cast<const bf16x8*>(src);
    *reinterpret_cast<bf16x8*>(base + half * 4096 + r * 2048 + tid * 8) = tmp;
#endif
  }
}

// ---------------------------------------------------------------------------
// Kernel S (triangular, grid-strided, cross-tile double-buffered):
// 1024 blocks; block handles tiles {bid, bid+1024, bid+2048?}.  Per tile:
// issue NEXT tile's q-panel prefetch into buf^1, compute current from buf
// (prefetch hides under ds_read/MFMA/exp), end-barrier drains vmcnt.
// Row-sums -> rowPart[p-rows][q]; col-sums -> rowPart[q-rows][p] (p!=q).
// ---------------------------------------------------------------------------
__global__ __launch_bounds__(256) void simsum_tri_kernel(
    const u16* __restrict__ Gb, float* __restrict__ rowPart) {
  __shared__ u16 Bs[2][2 * 64 * CDIM];   // 2 x 16KB double-buffered q-panel
  __shared__ float colRed[4][128];       // 2 KB

  const int tid  = threadIdx.x;
  const int lane = tid & 63;
  const int wave = tid >> 6;
  const int lrow = lane & 15;
  const int kh   = lane >> 4;
  const int srow = tid >> 3;
  const int ssl  = (tid & 7) ^ (srow & 7);
  const int sp0  = ((kh ^ (lrow & 7)) << 3);
  const int sp1  = (((4 + kh) ^ (lrow & 7)) << 3);

  int tile = blockIdx.x;
  int p, q;
  tri_decode(tile, &p, &q);

  // Prologue: stage first tile's q-panel into buf 0.
  stage_tile(Bs[0], Gb, q * 128,      0, tid, wave, srow, ssl);
  stage_tile(Bs[0], Gb, q * 128 + 64, 1, tid, wave, srow, ssl);
  __syncthreads();

  int buf = 0;
  while (true) {
    // Issue next tile's prefetch FIRST (overlaps with this tile's compute).
    const int ntile = tile + SBLK;
    int np2 = 0, nq2 = 0;
    const bool haveNext = (ntile < NPAIR);
    if (haveNext) {
      tri_decode(ntile, &np2, &nq2);
      stage_tile(Bs[buf ^ 1], Gb, nq2 * 128,      0, tid, wave, srow, ssl);
      stage_tile(Bs[buf ^ 1], Gb, nq2 * 128 + 64, 1, tid, wave, srow, ssl);
    }

    const int p0 = p * 128, q0 = q * 128;
    const int i0 = p0 + wave * 32;

    // A fragments (scaled in-register).  bf16x8* steps 8 shorts.
    const bf16x8* arowA = reinterpret_cast<const bf16x8*>(
        Gb + (size_t)(i0 + lrow) * CDIM + kh * 8);
    const bf16x8* arowB = reinterpret_cast<const bf16x8*>(
        Gb + (size_t)(i0 + 16 + lrow) * CDIM + kh * 8);
    bf16x8 aA0 = scale8(arowA[0]), aA1 = scale8(arowA[4]);
    bf16x8 aB0 = scale8(arowB[0]), aB1 = scale8(arowB[4]);

    float accA[4][4], accB[4][4];
#pragma unroll
    for (int nf = 0; nf < 4; ++nf)
#pragma unroll
      for (int r = 0; r < 4; ++r) { accA[nf][r] = 0.f; accB[nf][r] = 0.f; }
    float colAcc[2][4];

#pragma unroll
    for (int t = 0; t < 2; ++t) {
      const u16* bs = Bs[buf] + t * 4096;
#pragma unroll
      for (int nf = 0; nf < 4; ++nf) {
        const int rb = (nf * 16 + lrow) * CDIM;
        bf16x8 b0 = *reinterpret_cast<const bf16x8*>(bs + rb + sp0);
        bf16x8 b1 = *reinterpret_cast<const bf16x8*>(bs + rb + sp1);
        f32x4 z = {0.f, 0.f, 0.f, 0.f};
        f32x4 tA = __builtin_amdgcn_mfma_f32_16x16x32_bf16(aA0, b0, z, 0, 0, 0);
        tA = __builtin_amdgcn_mfma_f32_16x16x32_bf16(aA1, b1, tA, 0, 0, 0);
        f32x4 tB = __builtin_amdgcn_mfma_f32_16x16x32_bf16(aB0, b0, z, 0, 0, 0);
        tB = __builtin_amdgcn_mfma_f32_16x16x32_bf16(aB1, b1, tB, 0, 0, 0);
        float cp = 0.f;
#pragma unroll
        for (int r = 0; r < 4; ++r) {
          float eA = EXPFN(tA[r]);
          float eB = EXPFN(tB[r]);
          accA[nf][r] += eA;
          accB[nf][r] += eB;
          cp += eA + eB;
        }
        colAcc[t][nf] = cp;
      }
    }

    // Row-sums -> rowPart[p-rows][q]
#pragma unroll
    for (int r = 0; r < 4; ++r) {
      float vA = (accA[0][r] + accA[1][r]) + (accA[2][r] + accA[3][r]);
      float vB = (accB[0][r] + accB[1][r]) + (accB[2][r] + accB[3][r]);
      vA += __shfl_xor(vA, 1, 16);
      vA += __shfl_xor(vA, 2, 16);
      vA += __shfl_xor(vA, 4, 16);
      vA += __shfl_xor(vA, 8, 16);
      vB += __shfl_xor(vB, 1, 16);
      vB += __shfl_xor(vB, 2, 16);
      vB += __shfl_xor(vB, 4, 16);
      vB += __shfl_xor(vB, 8, 16);
      if (lrow == 0) {
        rowPart[(size_t)(i0 + kh * 4 + r) * NP + q] = vA;
        rowPart[(size_t)(i0 + 16 + kh * 4 + r) * NP + q] = vB;
      }
    }

    // Col-sums -> rowPart[q-rows][p] (p!=q; block-uniform branch)
    if (p != q) {
#pragma unroll
      for (int t = 0; t < 2; ++t)
#pragma unroll
        for (int nf = 0; nf < 4; ++nf) {
          float c = colAcc[t][nf];
          c += __shfl_xor(c, 16, 64);
          c += __shfl_xor(c, 32, 64);
          if (kh == 0) colRed[wave][t * 64 + nf * 16 + lrow] = c;
        }
      __syncthreads();
      if (tid < 128) {
        float s = (colRed[0][tid] + colRed[1][tid]) +
                  (colRed[2][tid] + colRed[3][tid]);
        rowPart[(size_t)(q0 + tid) * NP + p] = s;
      }
    }

    __syncthreads();   // drains prefetch vmcnt; protects Bs/colRed for reuse
    if (!haveNext) break;
    tile = ntile;
    p = np2;
    q = nq2;
    buf ^= 1;
  }
}

// ---------------------------------------------------------------------------
// Kernel F (fused): per-block partials; last block (device-scope counter,
// 64 RMWs on one line — proven scale) reduces in fixed order, writes scalar.
// ---------------------------------------------------------------------------
__global__ __launch_bounds__(256) void finpart_kernel(
    const u16* __restrict__ Gb, const float* __restrict__ rowPart,
    float* __restrict__ partA, float* __restrict__ partB,
    unsigned* __restrict__ counter, float* __restrict__ out) {
  __shared__ float sA[256];
  __shared__ float sB[256];
  __shared__ int lastFlag;
  const int tid = threadIdx.x, b = blockIdx.x;

  float logAcc = 0.f;
  if (tid < 128) {
    const int row = b * 128 + tid;
    const float4* rp = reinterpret_cast<const float4*>(rowPart + (size_t)row * NP);
    float s = 0.f;
#pragma unroll
    for (int c = 0; c < NP / 4; ++c) {
      float4 v = rp[c];
      s += (v.x + v.y) + (v.z + v.w);
    }
    logAcc = logf(s - EXP10);
  }
  float cross = 0.f;
  if (tid < 64) {
    const int u = b * 64 + tid;
    const unsigned* r0 = reinterpret_cast<const unsigned*>(Gb + (size_t)u * CDIM);
    const unsigned* r1 =
        reinterpret_cast<const unsigned*>(Gb + (size_t)(u + NLOC) * CDIM);
#pragma unroll
    for (int c = 0; c < 32; ++c) {
      unsigned a = r0[c], bb = r1[c];
      cross += bf2f(a & 0xffffu) * bf2f(bb & 0xffffu) + bf2f(a >> 16) * bf2f(bb >> 16);
    }
  }
  sA[tid] = logAcc;
  sB[tid] = cross;
  __syncthreads();
  for (int s = 128; s > 0; s >>= 1) {
    if (tid < s) { sA[tid] += sA[tid + s]; sB[tid] += sB[tid + s]; }
    __syncthreads();
  }
  if (tid == 0) {
    __hip_atomic_store(&partA[b], sA[0], __ATOMIC_RELAXED, __HIP_MEMORY_SCOPE_AGENT);
    __hip_atomic_store(&partB[b], sB[0], __ATOMIC_RELAXED, __HIP_MEMORY_SCOPE_AGENT);
    __threadfence();                          // release partials device-wide
    unsigned old = atomicAdd(counter, 1u);    // device-scope by default
    lastFlag = (old == 63u) ? 1 : 0;
  }
  __syncthreads();

  if (lastFlag && tid < 64) {
    float a = __hip_atomic_load(&partA[tid], __ATOMIC_RELAXED, __HIP_MEMORY_SCOPE_AGENT);
    float c = __hip_atomic_load(&partB[tid], __ATOMIC_RELAXED, __HIP_MEMORY_SCOPE_AGENT);
#pragma unroll
    for (int s = 1; s < 64; s <<= 1) {        // fixed-order butterfly
      a += __shfl_xor(a, s, 64);
      c += __shfl_xor(c, s, 64);
    }
    if (tid == 0) out[0] = (a - 2.0f * TINV * c) / (float)NROW;
  }
}

// ---------------------------------------------------------------------------
extern "C" void kernel_launch(void* const* d_in, const int* in_sizes, int n_in,
                              void* d_out, int out_size, void* d_ws, size_t ws_size,
                              hipStream_t stream) {
  const float* emb0 = (const float*)d_in[0];
  const float* emb1 = (const float*)d_in[1];
  const float* loc0 = (const float*)d_in[2];
  const float* loc1 = (const float*)d_in[3];
  float* out = (float*)d_out;
  char* ws = (char*)d_ws;

  // Layout: Gb 1MB | rowPart 2MB | partA 256B | partB 256B | counter
  u16* Gb           = (u16*)ws;
  float* rowPart    = (float*)(ws + (1ull << 20));
  float* partA      = (float*)(ws + (3ull << 20));
  float* partB      = (float*)(ws + (3ull << 20) + 256);
  unsigned* counter = (unsigned*)(ws + (3ull << 20) + 512);

  dim3 gg(128, 4);
  gatherc_kernel<<<gg, 256, 0, stream>>>(emb0, emb1, loc0, loc1, Gb, counter);
  simsum_tri_kernel<<<SBLK, 256, 0, stream>>>(Gb, rowPart);
  finpart_kernel<<<64, 256, 0, stream>>>(Gb, rowPart, partA, partB, counter, out);
}

// Round 14
// 41.650 us; speedup vs baseline: 1.0538x; 1.0538x over previous
//
#include <hip/hip_runtime.h>
#include <math.h>

// Problem constants (B=1, C=64, H=W=256, N=4096, T=0.1)
#define HW2     65536
#define NLOC    4096
#define NROW    8192
#define CDIM    64
#define TINV    10.0f
#define EXP10   22026.465794806718f   // exp(1/T)
#define NP      64                    // 128-row panels
#define NPAIR   2080                  // NP*(NP+1)/2

#if __has_builtin(__builtin_amdgcn_exp2f)
#define ASCALE  14.426950408889634f   // 10 * log2(e)
#define EXPFN(x) __builtin_amdgcn_exp2f(x)
#else
#define ASCALE  10.0f
#define EXPFN(x) __expf(x)
#endif

typedef __attribute__((ext_vector_type(8))) short bf16x8;
typedef __attribute__((ext_vector_type(4))) float f32x4;
typedef unsigned short u16;

__device__ __forceinline__ unsigned short f2bf(float f) {
  unsigned u = __builtin_bit_cast(unsigned, f);
  u += 0x7FFFu + ((u >> 16) & 1u);   // RNE
  return (unsigned short)(u >> 16);
}
__device__ __forceinline__ float bf2f(unsigned u16v) {
  unsigned u = u16v << 16;
  return __builtin_bit_cast(float, u);
}
// Scale a bf16x8 fragment by ASCALE with RNE re-round (bit-identical to a
// materialized Ga; validated R9-R13, absmax 0).
__device__ __forceinline__ bf16x8 scale8(bf16x8 r) {
  bf16x8 o;
#pragma unroll
  for (int j = 0; j < 8; ++j)
    o[j] = (short)f2bf(bf2f((unsigned short)r[j]) * ASCALE);
  return o;
}

// ---------------------------------------------------------------------------
// Kernel FG (filtered window gather): block = (64-position window, emb).
// All reads coalesced (16B/lane) instead of the scatter's 64-distinct-line
// wave-instrs.  Tile loads issued FIRST (registers), loc scan hides under
// their latency; 64-entry list (avg 4 hits); n==0 early-exit; Gb only.
// Overflow (P ~ 1e-60) falls back to direct scattered copy — deterministic.
// ---------------------------------------------------------------------------
__global__ __launch_bounds__(256) void fgather_kernel(
    const float* __restrict__ emb0, const float* __restrict__ emb1,
    const float* __restrict__ loc0, const float* __restrict__ loc1,
    u16* __restrict__ Gb, unsigned* __restrict__ counter) {
  __shared__ u16 T[64 * 72];          // [pos][ch] bf16, pad 72 (9 KB)
  __shared__ unsigned list[64];
  __shared__ unsigned nE;

  const int tid = threadIdx.x;
  const int win = blockIdx.x;         // 0..1023
  const int eb  = blockIdx.y;
  const float* emb = eb ? emb1 : emb0;
  const float* loc = eb ? loc1 : loc0;
  const int w0 = win * 64;

  if (win == 0 && eb == 0 && tid == 0) *counter = 0u;
  if (tid == 0) nE = 0;

  // Issue the 16-KB tile read first: 4 independent float4 loads per thread.
  const int cB = tid >> 4;            // channel within quarter
  const int x  = tid & 15;
  float4 v[4];
#pragma unroll
  for (int q = 0; q < 4; ++q)
    v[q] = *reinterpret_cast<const float4*>(
        &emb[(size_t)(q * 16 + cB) * HW2 + w0 + x * 4]);

  __syncthreads();                    // nE=0 visible

  // Scan this emb's 4096 locations; collect window hits (loads in flight).
  for (int it = tid; it < NLOC; it += 256) {
    float2 lv = *reinterpret_cast<const float2*>(&loc[it * 2]);
    int ind = (int)floorf(lv.x) * 256 + (int)floorf(lv.y);
    if ((ind >> 6) == win) {
      unsigned slot = atomicAdd(&nE, 1u);
      if (slot < 64u) {
        list[slot] = ((unsigned)it << 6) | (unsigned)(ind & 63);
      } else {                        // ~never: direct scattered fallback
        for (int c = 0; c < CDIM; ++c)
          Gb[(size_t)(it + eb * NLOC) * CDIM + c] =
              f2bf(emb[(size_t)c * HW2 + ind]);
      }
    }
  }
  __syncthreads();

  const int n = (int)((nE < 64u) ? nE : 64u);
  if (n == 0) return;                 // block-uniform: skip tile staging

  // Stage tile transposed into LDS (bf16).
#pragma unroll
  for (int q = 0; q < 4; ++q) {
    const int c = q * 16 + cB;
    T[(x * 4 + 0) * 72 + c] = f2bf(v[q].x);
    T[(x * 4 + 1) * 72 + c] = f2bf(v[q].y);
    T[(x * 4 + 2) * 72 + c] = f2bf(v[q].z);
    T[(x * 4 + 3) * 72 + c] = f2bf(v[q].w);
  }
  __syncthreads();

  // Emit hit rows: 8 threads per entry, 16B per thread, coalesced.
  const int ibase = eb * NLOC;
  const int c8 = tid & 7;
  for (int s = (tid >> 3); s < n; s += 32) {
    const unsigned ent = list[s];
    const int i = (int)(ent >> 6) + ibase;
    const int w = (int)(ent & 63u);
    bf16x8 r = *reinterpret_cast<const bf16x8*>(&T[w * 72 + c8 * 8]);
    *reinterpret_cast<bf16x8*>(&Gb[(size_t)i * CDIM + c8 * 8]) = r;
  }
}

// ---------------------------------------------------------------------------
// Staging: one 64-row x 128B tile, XOR seg-swizzle (measured 0 conflicts).
// ---------------------------------------------------------------------------
__device__ __forceinline__ void stage_tile(u16* Bs, const u16* __restrict__ Gb,
                                           int jb, int buf, int tid, int wave,
                                           int srow, int ssl) {
#pragma unroll
  for (int r = 0; r < 2; ++r) {
    const u16* src = Gb + (size_t)(jb + r * 32 + srow) * CDIM + ssl * 8;
#if __has_builtin(__builtin_amdgcn_global_load_lds)
    u16* dst = Bs + buf * 4096 + r * 2048 + wave * 512;
    __builtin_amdgcn_global_load_lds(
        (const __attribute__((address_space(1))) unsigned int*)src,
        (__attribute__((address_space(3))) unsigned int*)dst, 16, 0, 0);
#else
    bf16x8 tmp = *reinterpret_cast<const bf16x8*>(src);
    *reinterpret_cast<bf16x8*>(Bs + buf * 4096 + r * 2048 + tid * 8) = tmp;
#endif
  }
}

// ---------------------------------------------------------------------------
// Kernel S (triangular) — R12 champion, byte-identical.
// ---------------------------------------------------------------------------
__global__ __launch_bounds__(256) void simsum_tri_kernel(
    const u16* __restrict__ Gb, float* __restrict__ rowPart) {
  __shared__ u16 Bs[2 * 64 * CDIM];    // 16 KB
  __shared__ float colRed[4][128];     // 2 KB

  const int tid  = threadIdx.x;
  const int lane = tid & 63;
  const int wave = tid >> 6;
  const int lrow = lane & 15;
  const int kh   = lane >> 4;

  const int b = blockIdx.x;
  int p = (int)((129.0f - sqrtf(16641.0f - 8.0f * (float)b)) * 0.5f);
  if (p < 0) p = 0;
  if (p > NP - 1) p = NP - 1;
#pragma unroll
  for (int it = 0; it < 3; ++it) {
    if (p > 0 && (p * NP - p * (p - 1) / 2) > b) --p;
    else if (((p + 1) * NP - (p + 1) * p / 2) <= b) ++p;
  }
  const int q  = p + (b - (p * NP - p * (p - 1) / 2));
  const int p0 = p * 128, q0 = q * 128;
  const int i0 = p0 + wave * 32;

  const bf16x8* arowA =
      reinterpret_cast<const bf16x8*>(Gb + (size_t)(i0 + lrow) * CDIM + kh * 8);
  const bf16x8* arowB = reinterpret_cast<const bf16x8*>(
      Gb + (size_t)(i0 + 16 + lrow) * CDIM + kh * 8);
  bf16x8 aA0 = scale8(arowA[0]), aA1 = scale8(arowA[4]);
  bf16x8 aB0 = scale8(arowB[0]), aB1 = scale8(arowB[4]);

  const int srow = tid >> 3;
  const int ssl  = (tid & 7) ^ (srow & 7);
  stage_tile(Bs, Gb, q0,      0, tid, wave, srow, ssl);
  stage_tile(Bs, Gb, q0 + 64, 1, tid, wave, srow, ssl);
  __syncthreads();

  const int sp0 = ((kh ^ (lrow & 7)) << 3);
  const int sp1 = (((4 + kh) ^ (lrow & 7)) << 3);

  float accA[4][4], accB[4][4];
#pragma unroll
  for (int nf = 0; nf < 4; ++nf)
#pragma unroll
    for (int r = 0; r < 4; ++r) { accA[nf][r] = 0.f; accB[nf][r] = 0.f; }
  float colAcc[2][4];

#pragma unroll
  for (int t = 0; t < 2; ++t) {
    const u16* bs = Bs + t * 4096;
#pragma unroll
    for (int nf = 0; nf < 4; ++nf) {
      const int rb = (nf * 16 + lrow) * CDIM;
      bf16x8 b0 = *reinterpret_cast<const bf16x8*>(bs + rb + sp0);
      bf16x8 b1 = *reinterpret_cast<const bf16x8*>(bs + rb + sp1);
      f32x4 z = {0.f, 0.f, 0.f, 0.f};
      f32x4 tA = __builtin_amdgcn_mfma_f32_16x16x32_bf16(aA0, b0, z, 0, 0, 0);
      tA = __builtin_amdgcn_mfma_f32_16x16x32_bf16(aA1, b1, tA, 0, 0, 0);
      f32x4 tB = __builtin_amdgcn_mfma_f32_16x16x32_bf16(aB0, b0, z, 0, 0, 0);
      tB = __builtin_amdgcn_mfma_f32_16x16x32_bf16(aB1, b1, tB, 0, 0, 0);
      float cp = 0.f;
#pragma unroll
      for (int r = 0; r < 4; ++r) {
        float eA = EXPFN(tA[r]);
        float eB = EXPFN(tB[r]);
        accA[nf][r] += eA;
        accB[nf][r] += eB;
        cp += eA + eB;
      }
      colAcc[t][nf] = cp;
    }
  }

#pragma unroll
  for (int r = 0; r < 4; ++r) {
    float vA = (accA[0][r] + accA[1][r]) + (accA[2][r] + accA[3][r]);
    float vB = (accB[0][r] + accB[1][r]) + (accB[2][r] + accB[3][r]);
    vA += __shfl_xor(vA, 1, 16);
    vA += __shfl_xor(vA, 2, 16);
    vA += __shfl_xor(vA, 4, 16);
    vA += __shfl_xor(vA, 8, 16);
    vB += __shfl_xor(vB, 1, 16);
    vB += __shfl_xor(vB, 2, 16);
    vB += __shfl_xor(vB, 4, 16);
    vB += __shfl_xor(vB, 8, 16);
    if (lrow == 0) {
      rowPart[(size_t)(i0 + kh * 4 + r) * NP + q] = vA;
      rowPart[(size_t)(i0 + 16 + kh * 4 + r) * NP + q] = vB;
    }
  }

  if (p != q) {
#pragma unroll
    for (int t = 0; t < 2; ++t)
#pragma unroll
      for (int nf = 0; nf < 4; ++nf) {
        float c = colAcc[t][nf];
        c += __shfl_xor(c, 16, 64);
        c += __shfl_xor(c, 32, 64);
        if (kh == 0) colRed[wave][t * 64 + nf * 16 + lrow] = c;
      }
    __syncthreads();                  // p!=q is block-uniform -> legal
    if (tid < 128) {
      float s = (colRed[0][tid] + colRed[1][tid]) +
                (colRed[2][tid] + colRed[3][tid]);
      rowPart[(size_t)(q0 + tid) * NP + p] = s;
    }
  }
}

// ---------------------------------------------------------------------------
// Kernel F (fused) — R12 champion, byte-identical.
// ---------------------------------------------------------------------------
__global__ __launch_bounds__(256) void finpart_kernel(
    const u16* __restrict__ Gb, const float* __restrict__ rowPart,
    float* __restrict__ partA, float* __restrict__ partB,
    unsigned* __restrict__ counter, float* __restrict__ out) {
  __shared__ float sA[256];
  __shared__ float sB[256];
  __shared__ int lastFlag;
  const int tid = threadIdx.x, b = blockIdx.x;

  float logAcc = 0.f;
  if (tid < 128) {
    const int row = b * 128 + tid;
    const float4* rp = reinterpret_cast<const float4*>(rowPart + (size_t)row * NP);
    float s = 0.f;
#pragma unroll
    for (int c = 0; c < NP / 4; ++c) {
      float4 v = rp[c];
      s += (v.x + v.y) + (v.z + v.w);
    }
    logAcc = logf(s - EXP10);
  }
  float cross = 0.f;
  if (tid < 64) {
    const int u = b * 64 + tid;
    const unsigned* r0 = reinterpret_cast<const unsigned*>(Gb + (size_t)u * CDIM);
    const unsigned* r1 =
        reinterpret_cast<const unsigned*>(Gb + (size_t)(u + NLOC) * CDIM);
#pragma unroll
    for (int c = 0; c < 32; ++c) {
      unsigned a = r0[c], bb = r1[c];
      cross += bf2f(a & 0xffffu) * bf2f(bb & 0xffffu) + bf2f(a >> 16) * bf2f(bb >> 16);
    }
  }
  sA[tid] = logAcc;
  sB[tid] = cross;
  __syncthreads();
  for (int s = 128; s > 0; s >>= 1) {
    if (tid < s) { sA[tid] += sA[tid + s]; sB[tid] += sB[tid + s]; }
    __syncthreads();
  }
  if (tid == 0) {
    __hip_atomic_store(&partA[b], sA[0], __ATOMIC_RELAXED, __HIP_MEMORY_SCOPE_AGENT);
    __hip_atomic_store(&partB[b], sB[0], __ATOMIC_RELAXED, __HIP_MEMORY_SCOPE_AGENT);
    __threadfence();                          // release partials device-wide
    unsigned old = atomicAdd(counter, 1u);    // device-scope by default
    lastFlag = (old == 63u) ? 1 : 0;
  }
  __syncthreads();

  if (lastFlag && tid < 64) {
    float a = __hip_atomic_load(&partA[tid], __ATOMIC_RELAXED, __HIP_MEMORY_SCOPE_AGENT);
    float c = __hip_atomic_load(&partB[tid], __ATOMIC_RELAXED, __HIP_MEMORY_SCOPE_AGENT);
#pragma unroll
    for (int s = 1; s < 64; s <<= 1) {        // fixed-order butterfly
      a += __shfl_xor(a, s, 64);
      c += __shfl_xor(c, s, 64);
    }
    if (tid == 0) out[0] = (a - 2.0f * TINV * c) / (float)NROW;
  }
}

// ---------------------------------------------------------------------------
extern "C" void kernel_launch(void* const* d_in, const int* in_sizes, int n_in,
                              void* d_out, int out_size, void* d_ws, size_t ws_size,
                              hipStream_t stream) {
  const float* emb0 = (const float*)d_in[0];
  const float* emb1 = (const float*)d_in[1];
  const float* loc0 = (const float*)d_in[2];
  const float* loc1 = (const float*)d_in[3];
  float* out = (float*)d_out;
  char* ws = (char*)d_ws;

  // Layout: Gb 1MB | rowPart 2MB | partA 256B | partB 256B | counter
  u16* Gb           = (u16*)ws;
  float* rowPart    = (float*)(ws + (1ull << 20));
  float* partA      = (float*)(ws + (3ull << 20));
  float* partB      = (float*)(ws + (3ull << 20) + 256);
  unsigned* counter = (unsigned*)(ws + (3ull << 20) + 512);

  dim3 fg(1024, 2);
  fgather_kernel<<<fg, 256, 0, stream>>>(emb0, emb1, loc0, loc1, Gb, counter);
  simsum_tri_kernel<<<NPAIR, 256, 0, stream>>>(Gb, rowPart);
  finpart_kernel<<<64, 256, 0, stream>>>(Gb, rowPart, partA, partB, counter, out);
}

// Round 15
// 37.366 us; speedup vs baseline: 1.1747x; 1.1147x over previous
//
#include <hip/hip_runtime.h>
#include <math.h>

// Problem constants (B=1, C=64, H=W=256, N=4096, T=0.1)
#define HW2     65536
#define NLOC    4096
#define NROW    8192
#define CDIM    64
#define TINV    10.0f
#define EXP10   22026.465794806718f   // exp(1/T)
#define NP      64                    // 128-row panels
#define NPAIR   2080                  // NP*(NP+1)/2

#if __has_builtin(__builtin_amdgcn_exp2f)
#define ASCALE  14.426950408889634f   // 10 * log2(e)
#define EXPFN(x) __builtin_amdgcn_exp2f(x)
#else
#define ASCALE  10.0f
#define EXPFN(x) __expf(x)
#endif

typedef __attribute__((ext_vector_type(8))) short bf16x8;
typedef __attribute__((ext_vector_type(4))) float f32x4;
typedef unsigned short u16;

__device__ __forceinline__ unsigned short f2bf(float f) {
  unsigned u = __builtin_bit_cast(unsigned, f);
  u += 0x7FFFu + ((u >> 16) & 1u);   // RNE
  return (unsigned short)(u >> 16);
}
__device__ __forceinline__ float bf2f(unsigned u16v) {
  unsigned u = u16v << 16;
  return __builtin_bit_cast(float, u);
}
// Scale a bf16x8 fragment by ASCALE with RNE re-round (bit-identical to a
// materialized Ga; validated R9-R14, absmax 0).
__device__ __forceinline__ bf16x8 scale8(bf16x8 r) {
  bf16x8 o;
#pragma unroll
  for (int j = 0; j < 8; ++j)
    o[j] = (short)f2bf(bf2f((unsigned short)r[j]) * ASCALE);
  return o;
}

// ---------------------------------------------------------------------------
// Kernel GC (channel-major gather): grid (128,8) = 1024 blocks (4/CU, 2x the
// R12 MLP).  Block = 64 gather-rows x 8 channels; per thread 2 independent
// scattered loads, each wave-instr confined to ONE 256-KB channel slab
// (R8-proven locality).  16-B per-row writes preserved.  Writes Gb only;
// block (0,0) zeroes the finpart counter.
// ---------------------------------------------------------------------------
__global__ __launch_bounds__(256) void gatherc_kernel(
    const float* __restrict__ emb0, const float* __restrict__ emb1,
    const float* __restrict__ loc0, const float* __restrict__ loc1,
    u16* __restrict__ Gb, unsigned* __restrict__ counter) {
  __shared__ int ind[64];
  __shared__ u16 Gs[64][9];           // pad 9: row stride 18B, conflict-free

  const int tid   = threadIdx.x;
  const int chunk = blockIdx.x;       // 0..127 -> rows chunk*64..+64
  const int cg    = blockIdx.y;       // 0..7   -> channels cg*8..+8
  const int eb    = chunk >> 6;
  const float* emb = eb ? emb1 : emb0;
  const float* loc = eb ? loc1 : loc0;

  if (chunk == 0 && cg == 0 && tid == 0) *counter = 0u;

  if (tid < 64) {
    const int u = (chunk & 63) * 64 + tid;
    float2 lv = *reinterpret_cast<const float2*>(&loc[u * 2]);
    ind[tid] = (int)floorf(lv.x) * 256 + (int)floorf(lv.y);
  }
  __syncthreads();

  const int row = tid & 63;
  const int cq  = tid >> 6;           // 0..3
  const int pos = ind[row];
  // wave cq: all 64 lanes scatter within slab (cg*8+cq), then (cg*8+cq+4)
  float v0 = emb[(size_t)(cg * 8 + cq) * HW2 + pos];
  float v1 = emb[(size_t)(cg * 8 + cq + 4) * HW2 + pos];
  Gs[row][cq]     = f2bf(v0);
  Gs[row][cq + 4] = f2bf(v1);
  __syncthreads();

  if (tid < 64) {
    bf16x8 v = *reinterpret_cast<const bf16x8*>(&Gs[tid][0]);
    *reinterpret_cast<bf16x8*>(
        &Gb[(size_t)(chunk * 64 + tid) * CDIM + cg * 8]) = v;
  }
}

// ---------------------------------------------------------------------------
// Staging: one 64-row x 128B tile, XOR seg-swizzle (measured 0 conflicts).
// ---------------------------------------------------------------------------
__device__ __forceinline__ void stage_tile(u16* Bs, const u16* __restrict__ Gb,
                                           int jb, int buf, int tid, int wave,
                                           int srow, int ssl) {
#pragma unroll
  for (int r = 0; r < 2; ++r) {
    const u16* src = Gb + (size_t)(jb + r * 32 + srow) * CDIM + ssl * 8;
#if __has_builtin(__builtin_amdgcn_global_load_lds)
    u16* dst = Bs + buf * 4096 + r * 2048 + wave * 512;
    __builtin_amdgcn_global_load_lds(
        (const __attribute__((address_space(1))) unsigned int*)src,
        (__attribute__((address_space(3))) unsigned int*)dst, 16, 0, 0);
#else
    bf16x8 tmp = *reinterpret_cast<const bf16x8*>(src);
    *reinterpret_cast<bf16x8*>(Bs + buf * 4096 + r * 2048 + tid * 8) = tmp;
#endif
  }
}

// ---------------------------------------------------------------------------
// Kernel S (triangular) — R12 champion, byte-identical.
// ---------------------------------------------------------------------------
__global__ __launch_bounds__(256) void simsum_tri_kernel(
    const u16* __restrict__ Gb, float* __restrict__ rowPart) {
  __shared__ u16 Bs[2 * 64 * CDIM];    // 16 KB
  __shared__ float colRed[4][128];     // 2 KB

  const int tid  = threadIdx.x;
  const int lane = tid & 63;
  const int wave = tid >> 6;
  const int lrow = lane & 15;
  const int kh   = lane >> 4;

  const int b = blockIdx.x;
  int p = (int)((129.0f - sqrtf(16641.0f - 8.0f * (float)b)) * 0.5f);
  if (p < 0) p = 0;
  if (p > NP - 1) p = NP - 1;
#pragma unroll
  for (int it = 0; it < 3; ++it) {
    if (p > 0 && (p * NP - p * (p - 1) / 2) > b) --p;
    else if (((p + 1) * NP - (p + 1) * p / 2) <= b) ++p;
  }
  const int q  = p + (b - (p * NP - p * (p - 1) / 2));
  const int p0 = p * 128, q0 = q * 128;
  const int i0 = p0 + wave * 32;

  const bf16x8* arowA =
      reinterpret_cast<const bf16x8*>(Gb + (size_t)(i0 + lrow) * CDIM + kh * 8);
  const bf16x8* arowB = reinterpret_cast<const bf16x8*>(
      Gb + (size_t)(i0 + 16 + lrow) * CDIM + kh * 8);
  bf16x8 aA0 = scale8(arowA[0]), aA1 = scale8(arowA[4]);
  bf16x8 aB0 = scale8(arowB[0]), aB1 = scale8(arowB[4]);

  const int srow = tid >> 3;
  const int ssl  = (tid & 7) ^ (srow & 7);
  stage_tile(Bs, Gb, q0,      0, tid, wave, srow, ssl);
  stage_tile(Bs, Gb, q0 + 64, 1, tid, wave, srow, ssl);
  __syncthreads();

  const int sp0 = ((kh ^ (lrow & 7)) << 3);
  const int sp1 = (((4 + kh) ^ (lrow & 7)) << 3);

  float accA[4][4], accB[4][4];
#pragma unroll
  for (int nf = 0; nf < 4; ++nf)
#pragma unroll
    for (int r = 0; r < 4; ++r) { accA[nf][r] = 0.f; accB[nf][r] = 0.f; }
  float colAcc[2][4];

#pragma unroll
  for (int t = 0; t < 2; ++t) {
    const u16* bs = Bs + t * 4096;
#pragma unroll
    for (int nf = 0; nf < 4; ++nf) {
      const int rb = (nf * 16 + lrow) * CDIM;
      bf16x8 b0 = *reinterpret_cast<const bf16x8*>(bs + rb + sp0);
      bf16x8 b1 = *reinterpret_cast<const bf16x8*>(bs + rb + sp1);
      f32x4 z = {0.f, 0.f, 0.f, 0.f};
      f32x4 tA = __builtin_amdgcn_mfma_f32_16x16x32_bf16(aA0, b0, z, 0, 0, 0);
      tA = __builtin_amdgcn_mfma_f32_16x16x32_bf16(aA1, b1, tA, 0, 0, 0);
      f32x4 tB = __builtin_amdgcn_mfma_f32_16x16x32_bf16(aB0, b0, z, 0, 0, 0);
      tB = __builtin_amdgcn_mfma_f32_16x16x32_bf16(aB1, b1, tB, 0, 0, 0);
      float cp = 0.f;
#pragma unroll
      for (int r = 0; r < 4; ++r) {
        float eA = EXPFN(tA[r]);
        float eB = EXPFN(tB[r]);
        accA[nf][r] += eA;
        accB[nf][r] += eB;
        cp += eA + eB;
      }
      colAcc[t][nf] = cp;
    }
  }

#pragma unroll
  for (int r = 0; r < 4; ++r) {
    float vA = (accA[0][r] + accA[1][r]) + (accA[2][r] + accA[3][r]);
    float vB = (accB[0][r] + accB[1][r]) + (accB[2][r] + accB[3][r]);
    vA += __shfl_xor(vA, 1, 16);
    vA += __shfl_xor(vA, 2, 16);
    vA += __shfl_xor(vA, 4, 16);
    vA += __shfl_xor(vA, 8, 16);
    vB += __shfl_xor(vB, 1, 16);
    vB += __shfl_xor(vB, 2, 16);
    vB += __shfl_xor(vB, 4, 16);
    vB += __shfl_xor(vB, 8, 16);
    if (lrow == 0) {
      rowPart[(size_t)(i0 + kh * 4 + r) * NP + q] = vA;
      rowPart[(size_t)(i0 + 16 + kh * 4 + r) * NP + q] = vB;
    }
  }

  if (p != q) {
#pragma unroll
    for (int t = 0; t < 2; ++t)
#pragma unroll
      for (int nf = 0; nf < 4; ++nf) {
        float c = colAcc[t][nf];
        c += __shfl_xor(c, 16, 64);
        c += __shfl_xor(c, 32, 64);
        if (kh == 0) colRed[wave][t * 64 + nf * 16 + lrow] = c;
      }
    __syncthreads();                  // p!=q is block-uniform -> legal
    if (tid < 128) {
      float s = (colRed[0][tid] + colRed[1][tid]) +
                (colRed[2][tid] + colRed[3][tid]);
      rowPart[(size_t)(q0 + tid) * NP + p] = s;
    }
  }
}

// ---------------------------------------------------------------------------
// Kernel F (fused) — R12 champion, byte-identical.
// ---------------------------------------------------------------------------
__global__ __launch_bounds__(256) void finpart_kernel(
    const u16* __restrict__ Gb, const float* __restrict__ rowPart,
    float* __restrict__ partA, float* __restrict__ partB,
    unsigned* __restrict__ counter, float* __restrict__ out) {
  __shared__ float sA[256];
  __shared__ float sB[256];
  __shared__ int lastFlag;
  const int tid = threadIdx.x, b = blockIdx.x;

  float logAcc = 0.f;
  if (tid < 128) {
    const int row = b * 128 + tid;
    const float4* rp = reinterpret_cast<const float4*>(rowPart + (size_t)row * NP);
    float s = 0.f;
#pragma unroll
    for (int c = 0; c < NP / 4; ++c) {
      float4 v = rp[c];
      s += (v.x + v.y) + (v.z + v.w);
    }
    logAcc = logf(s - EXP10);
  }
  float cross = 0.f;
  if (tid < 64) {
    const int u = b * 64 + tid;
    const unsigned* r0 = reinterpret_cast<const unsigned*>(Gb + (size_t)u * CDIM);
    const unsigned* r1 =
        reinterpret_cast<const unsigned*>(Gb + (size_t)(u + NLOC) * CDIM);
#pragma unroll
    for (int c = 0; c < 32; ++c) {
      unsigned a = r0[c], bb = r1[c];
      cross += bf2f(a & 0xffffu) * bf2f(bb & 0xffffu) + bf2f(a >> 16) * bf2f(bb >> 16);
    }
  }
  sA[tid] = logAcc;
  sB[tid] = cross;
  __syncthreads();
  for (int s = 128; s > 0; s >>= 1) {
    if (tid < s) { sA[tid] += sA[tid + s]; sB[tid] += sB[tid + s]; }
    __syncthreads();
  }
  if (tid == 0) {
    __hip_atomic_store(&partA[b], sA[0], __ATOMIC_RELAXED, __HIP_MEMORY_SCOPE_AGENT);
    __hip_atomic_store(&partB[b], sB[0], __ATOMIC_RELAXED, __HIP_MEMORY_SCOPE_AGENT);
    __threadfence();                          // release partials device-wide
    unsigned old = atomicAdd(counter, 1u);    // device-scope by default
    lastFlag = (old == 63u) ? 1 : 0;
  }
  __syncthreads();

  if (lastFlag && tid < 64) {
    float a = __hip_atomic_load(&partA[tid], __ATOMIC_RELAXED, __HIP_MEMORY_SCOPE_AGENT);
    float c = __hip_atomic_load(&partB[tid], __ATOMIC_RELAXED, __HIP_MEMORY_SCOPE_AGENT);
#pragma unroll
    for (int s = 1; s < 64; s <<= 1) {        // fixed-order butterfly
      a += __shfl_xor(a, s, 64);
      c += __shfl_xor(c, s, 64);
    }
    if (tid == 0) out[0] = (a - 2.0f * TINV * c) / (float)NROW;
  }
}

// ---------------------------------------------------------------------------
extern "C" void kernel_launch(void* const* d_in, const int* in_sizes, int n_in,
                              void* d_out, int out_size, void* d_ws, size_t ws_size,
                              hipStream_t stream) {
  const float* emb0 = (const float*)d_in[0];
  const float* emb1 = (const float*)d_in[1];
  const float* loc0 = (const float*)d_in[2];
  const float* loc1 = (const float*)d_in[3];
  float* out = (float*)d_out;
  char* ws = (char*)d_ws;

  // Layout: Gb 1MB | rowPart 2MB | partA 256B | partB 256B | counter
  u16* Gb           = (u16*)ws;
  float* rowPart    = (float*)(ws + (1ull << 20));
  float* partA      = (float*)(ws + (3ull << 20));
  float* partB      = (float*)(ws + (3ull << 20) + 256);
  unsigned* counter = (unsigned*)(ws + (3ull << 20) + 512);

  dim3 gg(128, 8);
  gatherc_kernel<<<gg, 256, 0, stream>>>(emb0, emb1, loc0, loc1, Gb, counter);
  simsum_tri_kernel<<<NPAIR, 256, 0, stream>>>(Gb, rowPart);
  finpart_kernel<<<64, 256, 0, stream>>>(Gb, rowPart, partA, partB, counter, out);
}